// Round 1
// baseline (470.652 us; speedup 1.0000x reference)
//
#include <hip/hip_runtime.h>
#include <math.h>

#define BB   4
#define LL   2048
#define DM   256
#define DI   512
#define DSN  16
#define HIDN 512
#define NCH  16
#define CHK  128          // LL / NCH
#define ROWS (BB*LL)      // 8192

__device__ __forceinline__ float sig_(float x) { return 1.f / (1.f + __expf(-x)); }

// ---------------- K1: xi = x @ W_in[0:512]^T  (8192x512, K=256) ----------------
__global__ __launch_bounds__(256) void k_gemm_xi(const float* __restrict__ x,
                                                 const float* __restrict__ Win,
                                                 float* __restrict__ xi) {
    __shared__ float As[64][17];
    __shared__ float Bs[64][17];
    const int tid = threadIdx.x;
    const int tx = tid & 15, ty = tid >> 4;
    const int m0 = blockIdx.x * 64;
    const int n0 = blockIdx.y * 64;
    const int lr = tid >> 2;          // 0..63
    const int lk = (tid & 3) << 2;    // 0,4,8,12
    float acc[4][4] = {};
    for (int k0 = 0; k0 < DM; k0 += 16) {
        float4 av = *(const float4*)(x   + (size_t)(m0 + lr) * DM + k0 + lk);
        float4 bv = *(const float4*)(Win + (size_t)(n0 + lr) * DM + k0 + lk);
        As[lr][lk]   = av.x; As[lr][lk+1] = av.y; As[lr][lk+2] = av.z; As[lr][lk+3] = av.w;
        Bs[lr][lk]   = bv.x; Bs[lr][lk+1] = bv.y; Bs[lr][lk+2] = bv.z; Bs[lr][lk+3] = bv.w;
        __syncthreads();
#pragma unroll
        for (int kk = 0; kk < 16; ++kk) {
            float a[4], b[4];
#pragma unroll
            for (int i = 0; i < 4; ++i) a[i] = As[ty*4+i][kk];
#pragma unroll
            for (int j = 0; j < 4; ++j) b[j] = Bs[tx*4+j][kk];
#pragma unroll
            for (int i = 0; i < 4; ++i)
#pragma unroll
                for (int j = 0; j < 4; ++j) acc[i][j] = fmaf(a[i], b[j], acc[i][j]);
        }
        __syncthreads();
    }
#pragma unroll
    for (int i = 0; i < 4; ++i) {
        const int m = m0 + ty*4 + i;
#pragma unroll
        for (int j = 0; j < 4; ++j)
            xi[(size_t)m * DI + n0 + tx*4 + j] = acc[i][j];
    }
}

// ---------------- K1b: z_last[b,d] = x[b,L-1,:] . W_in[512+d,:] ----------------
__global__ void k_zlast(const float* __restrict__ x, const float* __restrict__ Win,
                        float* __restrict__ zl) {
    int idx = blockIdx.x * 256 + threadIdx.x;   // 0..2047
    int b = idx >> 9, d = idx & (DI-1);
    const float* xr = x + (size_t)(b*LL + LL-1) * DM;
    const float* wr = Win + (size_t)(DI + d) * DM;
    float acc = 0.f;
    for (int k = 0; k < DM; k += 4) {
        float4 a = *(const float4*)(xr+k), w = *(const float4*)(wr+k);
        acc = fmaf(a.x,w.x, fmaf(a.y,w.y, fmaf(a.z,w.z, fmaf(a.w,w.w, acc))));
    }
    zl[idx] = acc;
}

// ---------------- K2: causal depthwise conv (k=4) + SiLU -> xs ----------------
__global__ void k_conv(const float* __restrict__ xi, const float* __restrict__ cw,
                       const float* __restrict__ cb, float* __restrict__ xs) {
    int idx = blockIdx.x * 256 + threadIdx.x;   // over ROWS*DI
    int d = idx & (DI-1);
    int r = idx >> 9;          // b*LL + l
    int l = r & (LL-1);
    float4 w = *(const float4*)(cw + d*4);
    float acc = cb[d];
    if (l >= 3) {
        acc = fmaf(w.x, xi[(size_t)(r-3)*DI + d], acc);
        acc = fmaf(w.y, xi[(size_t)(r-2)*DI + d], acc);
        acc = fmaf(w.z, xi[(size_t)(r-1)*DI + d], acc);
        acc = fmaf(w.w, xi[(size_t)(r  )*DI + d], acc);
    } else {
        const float wk[4] = {w.x, w.y, w.z, w.w};
#pragma unroll
        for (int k = 0; k < 4; ++k) {
            int lt = l - 3 + k;
            if (lt >= 0) acc = fmaf(wk[k], xi[(size_t)(r-3+k)*DI + d], acc);
        }
    }
    xs[idx] = acc * sig_(acc);   // silu
}

// ---------------- K3: proj = xs @ W_xproj^T  (8192 x 48, K=512) ----------------
__global__ __launch_bounds__(192) void k_proj(const float* __restrict__ xs,
                                              const float* __restrict__ Wx,
                                              float* __restrict__ proj) {
    int tid = threadIdx.x;            // 0..191
    int e  = tid % 48;
    int rl = tid / 48;                // 0..3
    int row = blockIdx.x * 4 + rl;
    const float* xr = xs + (size_t)row * DI;
    const float* wr = Wx + (size_t)e * DI;
    float acc = 0.f;
    for (int k = 0; k < DI; k += 4) {
        float4 a = *(const float4*)(xr+k), w = *(const float4*)(wr+k);
        acc = fmaf(a.x,w.x, fmaf(a.y,w.y, fmaf(a.z,w.z, fmaf(a.w,w.w, acc))));
    }
    proj[(size_t)row*48 + e] = acc;
}

// ---------------- K4: dt = softplus(proj[:, :16] @ W_dt^T + b_dt) ----------------
__global__ void k_dt(const float* __restrict__ proj, const float* __restrict__ Wdt,
                     const float* __restrict__ bdt, float* __restrict__ dt) {
    int idx = blockIdx.x * 256 + threadIdx.x;   // over ROWS*DI
    int d = idx & (DI-1);
    int row = idx >> 9;
    const float* pr = proj + (size_t)row * 48;
    const float* wr = Wdt + d * 16;
    float acc = bdt[d];
#pragma unroll
    for (int k = 0; k < 16; k += 4) {
        float4 a = *(const float4*)(pr+k), w = *(const float4*)(wr+k);
        acc = fmaf(a.x,w.x, fmaf(a.y,w.y, fmaf(a.z,w.z, fmaf(a.w,w.w, acc))));
    }
    dt[idx] = (acc > 20.f) ? acc : log1pf(__expf(acc));   // softplus
}

// ---------------- K5: per-chunk scan ----------------
// lane g -> (b, c, d, s): s = g&15, d = (g>>4)&511, c = (g>>13)&15, b = g>>17
__global__ __launch_bounds__(256) void k_scan1(const float* __restrict__ dt,
                                               const float* __restrict__ xs,
                                               const float* __restrict__ proj,
                                               const float* __restrict__ Alog,
                                               float* __restrict__ hc,
                                               float* __restrict__ Dsum) {
    int g = blockIdx.x * 256 + threadIdx.x;
    int s = g & 15;
    int d = (g >> 4) & (DI-1);
    int c = (g >> 13) & (NCH-1);
    int b = g >> 17;
    float Af = -__expf(Alog[d*DSN + s]);
    float h = 0.f, Dl = 0.f;
    int rbase = b*LL + c*CHK;
    for (int i = 0; i < CHK; ++i) {
        int r = rbase + i;
        float dtv = dt[(size_t)r*DI + d];
        float xsv = xs[(size_t)r*DI + d];
        float bcv = proj[(size_t)r*48 + 16 + s];
        h = __expf(dtv * Af) * h + dtv * bcv * xsv;
        Dl += dtv;
    }
    hc[(size_t)((((b<<9)|d)<<4 | s)<<4) + c] = h;
    if (s == 0) Dsum[(((b<<9)|d)<<4) + c] = Dl;
}

// ---------------- K6: cross-chunk combine + y_last epilogue ----------------
__global__ __launch_bounds__(256) void k_scan2(const float* __restrict__ hc,
                                               const float* __restrict__ Dsum,
                                               const float* __restrict__ Alog,
                                               const float* __restrict__ proj,
                                               const float* __restrict__ xs,
                                               const float* __restrict__ Dp,
                                               const float* __restrict__ zl,
                                               float* __restrict__ ypre) {
    int g = blockIdx.x * 256 + threadIdx.x;   // 0..32767
    int s = g & 15;
    int d = (g >> 4) & (DI-1);
    int b = g >> 13;
    float Af = -__expf(Alog[d*DSN + s]);
    const float* hcb = hc + (size_t)((((b<<9)|d)<<4 | s)<<4);
    const float* Db  = Dsum + ((((b<<9)|d))<<4);
    float h = 0.f, Ss = 0.f;
#pragma unroll
    for (int c = NCH-1; c >= 0; --c) {
        h = fmaf(__expf(Af * Ss), hcb[c], h);
        Ss += Db[c];
    }
    int rlast = b*LL + LL - 1;
    float v = h * proj[(size_t)rlast*48 + 32 + s];
    v += __shfl_xor(v, 8);
    v += __shfl_xor(v, 4);
    v += __shfl_xor(v, 2);
    v += __shfl_xor(v, 1);
    if (s == 0) {
        float y = v + xs[(size_t)rlast*DI + d] * Dp[d];
        float z = zl[b*DI + d];
        y *= z * sig_(z);             // * silu(z)
        ypre[b*DI + d] = y;
    }
}

// ---------------- K7: m = y_pre @ W_out^T  (4 x 256, K=512) ----------------
__global__ void k_mout(const float* __restrict__ ypre, const float* __restrict__ Wout,
                       float* __restrict__ m) {
    int idx = blockIdx.x * 256 + threadIdx.x;   // 0..1023
    int b = idx >> 8, o = idx & 255;
    const float* yr = ypre + b * DI;
    const float* wr = Wout + (size_t)o * DI;
    float acc = 0.f;
    for (int k = 0; k < DI; k += 4) {
        float4 a = *(const float4*)(yr+k), w = *(const float4*)(wr+k);
        acc = fmaf(a.x,w.x, fmaf(a.y,w.y, fmaf(a.z,w.z, fmaf(a.w,w.w, acc))));
    }
    m[idx] = acc;
}

// ---------------- K8: LSTM cell ----------------
__global__ void k_lstm(const float* __restrict__ m, const float* __restrict__ h0,
                       const float* __restrict__ c0, const float* __restrict__ Wih,
                       const float* __restrict__ Whh, const float* __restrict__ bih,
                       const float* __restrict__ bhh, float* __restrict__ out) {
    int idx = blockIdx.x * 256 + threadIdx.x;   // 0..2047
    int b = idx >> 9, j = idx & (HIDN-1);
    const float* mr = m + b * DM;
    const float* hr = h0 + b * HIDN;
    float gate[4];
#pragma unroll
    for (int q = 0; q < 4; ++q) {
        int jj = q * HIDN + j;
        float acc = bih[jj] + bhh[jj];
        const float* wi = Wih + (size_t)jj * DM;
        for (int k = 0; k < DM; k += 4) {
            float4 a = *(const float4*)(mr+k), w = *(const float4*)(wi+k);
            acc = fmaf(a.x,w.x, fmaf(a.y,w.y, fmaf(a.z,w.z, fmaf(a.w,w.w, acc))));
        }
        const float* wh = Whh + (size_t)jj * HIDN;
        for (int k = 0; k < HIDN; k += 4) {
            float4 a = *(const float4*)(hr+k), w = *(const float4*)(wh+k);
            acc = fmaf(a.x,w.x, fmaf(a.y,w.y, fmaf(a.z,w.z, fmaf(a.w,w.w, acc))));
        }
        gate[q] = acc;
    }
    float ig = sig_(gate[0]);
    float fg = sig_(gate[1]);
    float gg = tanhf(gate[2]);
    float og = sig_(gate[3]);
    float cn = fg * c0[idx] + ig * gg;
    float hn = og * tanhf(cn);
    out[idx] = hn;                 // h_new
    out[BB*HIDN + idx] = cn;       // c_new
}

extern "C" void kernel_launch(void* const* d_in, const int* in_sizes, int n_in,
                              void* d_out, int out_size, void* d_ws, size_t ws_size,
                              hipStream_t stream) {
    const float* x     = (const float*)d_in[0];
    const float* h0    = (const float*)d_in[1];
    const float* c0    = (const float*)d_in[2];
    const float* Win   = (const float*)d_in[3];
    const float* convw = (const float*)d_in[4];
    const float* convb = (const float*)d_in[5];
    const float* Wx    = (const float*)d_in[6];
    const float* Wdt   = (const float*)d_in[7];
    const float* bdt   = (const float*)d_in[8];
    const float* Alog  = (const float*)d_in[9];
    const float* Dp    = (const float*)d_in[10];
    const float* Wout  = (const float*)d_in[11];
    const float* Wih   = (const float*)d_in[12];
    const float* Whh   = (const float*)d_in[13];
    const float* bih   = (const float*)d_in[14];
    const float* bhh   = (const float*)d_in[15];

    float* ws   = (float*)d_ws;
    float* xi   = ws;                         // ROWS*DI  (reused as dt after K3)
    float* xs   = xi + (size_t)ROWS*DI;       // ROWS*DI
    float* proj = xs + (size_t)ROWS*DI;       // ROWS*48
    float* hc   = proj + (size_t)ROWS*48;     // BB*DI*DSN*NCH = 524288
    float* Dsum = hc + (size_t)BB*DI*DSN*NCH; // BB*DI*NCH = 32768
    float* zl   = Dsum + (size_t)BB*DI*NCH;   // BB*DI
    float* ypre = zl + (size_t)BB*DI;         // BB*DI
    float* mm   = ypre + (size_t)BB*DI;       // BB*DM
    float* out  = (float*)d_out;

    k_gemm_xi<<<dim3(ROWS/64, DI/64), 256, 0, stream>>>(x, Win, xi);
    k_zlast <<<BB*DI/256, 256, 0, stream>>>(x, Win, zl);
    k_conv  <<<(size_t)ROWS*DI/256, 256, 0, stream>>>(xi, convw, convb, xs);
    k_proj  <<<ROWS/4, 192, 0, stream>>>(xs, Wx, proj);
    k_dt    <<<(size_t)ROWS*DI/256, 256, 0, stream>>>(proj, Wdt, bdt, xi);
    k_scan1 <<<BB*DI*DSN*NCH/256, 256, 0, stream>>>(xi, xs, proj, Alog, hc, Dsum);
    k_scan2 <<<BB*DI*DSN/256, 256, 0, stream>>>(hc, Dsum, Alog, proj, xs, Dp, zl, ypre);
    k_mout  <<<BB*DM/256, 256, 0, stream>>>(ypre, Wout, mm);
    k_lstm  <<<BB*HIDN/256, 256, 0, stream>>>(mm, h0, c0, Wih, Whh, bih, bhh, out);
}

// Round 3
// 312.947 us; speedup vs baseline: 1.5039x; 1.5039x over previous
//
#include <hip/hip_runtime.h>
#include <math.h>

#define BB   4
#define LL   2048
#define DM   256
#define DI   512
#define DSN  16
#define HIDN 512
#define NCH  16
#define CHK  128          // LL / NCH
#define ROWS (BB*LL)      // 8192

__device__ __forceinline__ float sig_(float x) { return 1.f / (1.f + __expf(-x)); }
__device__ __forceinline__ float dot4(float4 a, float4 w, float acc) {
    return fmaf(a.x,w.x, fmaf(a.y,w.y, fmaf(a.z,w.z, fmaf(a.w,w.w, acc))));
}

// ---------------- K1: xi = x @ W_in[0:512]^T  (8192x512, K=256) ----------------
// LDS tiles stored transposed [k][m] so fragment reads are ds_read_b128.
__global__ __launch_bounds__(256) void k_gemm_xi(const float* __restrict__ x,
                                                 const float* __restrict__ Win,
                                                 float* __restrict__ xi) {
    __shared__ float As[16][68];   // [k][m], pitch 68 floats = 272 B (16B-aligned)
    __shared__ float Bs[16][68];   // [k][n]
    const int tid = threadIdx.x;
    const int tx = tid & 15, ty = tid >> 4;
    const int m0 = blockIdx.x * 64;
    const int n0 = blockIdx.y * 64;
    const int lr = tid >> 2;          // 0..63
    const int lk = (tid & 3) << 2;    // 0,4,8,12
    float acc[4][4] = {};
    for (int k0 = 0; k0 < DM; k0 += 16) {
        float4 av = *(const float4*)(x   + (size_t)(m0 + lr) * DM + k0 + lk);
        float4 bv = *(const float4*)(Win + (size_t)(n0 + lr) * DM + k0 + lk);
        As[lk+0][lr] = av.x; As[lk+1][lr] = av.y; As[lk+2][lr] = av.z; As[lk+3][lr] = av.w;
        Bs[lk+0][lr] = bv.x; Bs[lk+1][lr] = bv.y; Bs[lk+2][lr] = bv.z; Bs[lk+3][lr] = bv.w;
        __syncthreads();
#pragma unroll
        for (int kk = 0; kk < 16; ++kk) {
            float4 a4 = *(const float4*)&As[kk][ty*4];
            float4 b4 = *(const float4*)&Bs[kk][tx*4];
            float a[4] = {a4.x, a4.y, a4.z, a4.w};
            float b[4] = {b4.x, b4.y, b4.z, b4.w};
#pragma unroll
            for (int i = 0; i < 4; ++i)
#pragma unroll
                for (int j = 0; j < 4; ++j) acc[i][j] = fmaf(a[i], b[j], acc[i][j]);
        }
        __syncthreads();
    }
#pragma unroll
    for (int i = 0; i < 4; ++i) {
        const int m = m0 + ty*4 + i;
#pragma unroll
        for (int j = 0; j < 4; ++j)
            xi[(size_t)m * DI + n0 + tx*4 + j] = acc[i][j];
    }
}

// ---------------- K1b: z_last[b,d] = x[b,L-1,:] . W_in[512+d,:] ----------------
// 16 lanes per output, split-K shuffle reduce. grid 128 blocks.
__global__ __launch_bounds__(256) void k_zlast(const float* __restrict__ x,
                                               const float* __restrict__ Win,
                                               float* __restrict__ zl) {
    int sub = threadIdx.x & 15;
    int idx = blockIdx.x * 16 + (threadIdx.x >> 4);   // 0..2047
    int b = idx >> 9, d = idx & (DI-1);
    const float* xr = x + (size_t)(b*LL + LL-1) * DM + sub*16;
    const float* wr = Win + (size_t)(DI + d) * DM + sub*16;
    float acc = 0.f;
#pragma unroll
    for (int k = 0; k < 16; k += 4)
        acc = dot4(*(const float4*)(xr+k), *(const float4*)(wr+k), acc);
    acc += __shfl_xor(acc, 1); acc += __shfl_xor(acc, 2);
    acc += __shfl_xor(acc, 4); acc += __shfl_xor(acc, 8);
    if (sub == 0) zl[idx] = acc;
}

// ---------------- K2: causal depthwise conv (k=4) + SiLU -> xs ----------------
__global__ void k_conv(const float* __restrict__ xi, const float* __restrict__ cw,
                       const float* __restrict__ cb, float* __restrict__ xs) {
    int idx = blockIdx.x * 256 + threadIdx.x;   // over ROWS*DI
    int d = idx & (DI-1);
    int r = idx >> 9;          // b*LL + l
    int l = r & (LL-1);
    float4 w = *(const float4*)(cw + d*4);
    float acc = cb[d];
    if (l >= 3) {
        acc = fmaf(w.x, xi[(size_t)(r-3)*DI + d], acc);
        acc = fmaf(w.y, xi[(size_t)(r-2)*DI + d], acc);
        acc = fmaf(w.z, xi[(size_t)(r-1)*DI + d], acc);
        acc = fmaf(w.w, xi[(size_t)(r  )*DI + d], acc);
    } else {
        const float wk[4] = {w.x, w.y, w.z, w.w};
#pragma unroll
        for (int k = 0; k < 4; ++k) {
            int lt = l - 3 + k;
            if (lt >= 0) acc = fmaf(wk[k], xi[(size_t)(r-3+k)*DI + d], acc);
        }
    }
    xs[idx] = acc * sig_(acc);   // silu
}

// ---------------- K3: proj = xs @ W_xproj^T  (8192 x 48, K=512) ----------------
__global__ __launch_bounds__(192) void k_proj(const float* __restrict__ xs,
                                              const float* __restrict__ Wx,
                                              float* __restrict__ proj) {
    int tid = threadIdx.x;            // 0..191
    int e  = tid % 48;
    int rl = tid / 48;                // 0..3
    int row = blockIdx.x * 4 + rl;
    const float* xr = xs + (size_t)row * DI;
    const float* wr = Wx + (size_t)e * DI;
    float acc = 0.f;
    for (int k = 0; k < DI; k += 4)
        acc = dot4(*(const float4*)(xr+k), *(const float4*)(wr+k), acc);
    proj[(size_t)row*48 + e] = acc;
}

// ---------------- K4: dt = softplus(proj[:, :16] @ W_dt^T + b_dt) ----------------
__global__ void k_dt(const float* __restrict__ proj, const float* __restrict__ Wdt,
                     const float* __restrict__ bdt, float* __restrict__ dt) {
    int idx = blockIdx.x * 256 + threadIdx.x;   // over ROWS*DI
    int d = idx & (DI-1);
    int row = idx >> 9;
    const float* pr = proj + (size_t)row * 48;
    const float* wr = Wdt + d * 16;
    float acc = bdt[d];
#pragma unroll
    for (int k = 0; k < 16; k += 4)
        acc = dot4(*(const float4*)(pr+k), *(const float4*)(wr+k), acc);
    dt[idx] = (acc > 20.f) ? acc : log1pf(__expf(acc));   // softplus
}

// ---------------- K5: per-chunk scan ----------------
// lane g -> (b, c, d, s): s = g&15, d = (g>>4)&511, c = (g>>13)&15, b = g>>17
__global__ __launch_bounds__(256) void k_scan1(const float* __restrict__ dt,
                                               const float* __restrict__ xs,
                                               const float* __restrict__ proj,
                                               const float* __restrict__ Alog,
                                               float* __restrict__ hc,
                                               float* __restrict__ Dsum) {
    int g = blockIdx.x * 256 + threadIdx.x;
    int s = g & 15;
    int d = (g >> 4) & (DI-1);
    int c = (g >> 13) & (NCH-1);
    int b = g >> 17;
    float Af = -__expf(Alog[d*DSN + s]);
    float h = 0.f, Dl = 0.f;
    int rbase = b*LL + c*CHK;
    for (int i = 0; i < CHK; ++i) {
        int r = rbase + i;
        float dtv = dt[(size_t)r*DI + d];
        float xsv = xs[(size_t)r*DI + d];
        float bcv = proj[(size_t)r*48 + 16 + s];
        h = __expf(dtv * Af) * h + dtv * bcv * xsv;
        Dl += dtv;
    }
    hc[(size_t)((((b<<9)|d)<<4 | s)<<4) + c] = h;
    if (s == 0) Dsum[(((b<<9)|d)<<4) + c] = Dl;
}

// ---------------- K6: cross-chunk combine + y_last epilogue ----------------
__global__ __launch_bounds__(256) void k_scan2(const float* __restrict__ hc,
                                               const float* __restrict__ Dsum,
                                               const float* __restrict__ Alog,
                                               const float* __restrict__ proj,
                                               const float* __restrict__ xs,
                                               const float* __restrict__ Dp,
                                               const float* __restrict__ zl,
                                               float* __restrict__ ypre) {
    int g = blockIdx.x * 256 + threadIdx.x;   // 0..32767
    int s = g & 15;
    int d = (g >> 4) & (DI-1);
    int b = g >> 13;
    float Af = -__expf(Alog[d*DSN + s]);
    const float* hcb = hc + (size_t)((((b<<9)|d)<<4 | s)<<4);
    const float* Db  = Dsum + ((((b<<9)|d))<<4);
    float h = 0.f, Ss = 0.f;
#pragma unroll
    for (int c = NCH-1; c >= 0; --c) {
        h = fmaf(__expf(Af * Ss), hcb[c], h);
        Ss += Db[c];
    }
    int rlast = b*LL + LL - 1;
    float v = h * proj[(size_t)rlast*48 + 32 + s];
    v += __shfl_xor(v, 8);
    v += __shfl_xor(v, 4);
    v += __shfl_xor(v, 2);
    v += __shfl_xor(v, 1);
    if (s == 0) {
        float y = v + xs[(size_t)rlast*DI + d] * Dp[d];
        float z = zl[b*DI + d];
        y *= z * sig_(z);             // * silu(z)
        ypre[b*DI + d] = y;
    }
}

// ---------------- K7: m = y_pre @ W_out^T  (4 x 256, K=512) ----------------
// 16 lanes per output. grid 64 blocks.
__global__ __launch_bounds__(256) void k_mout(const float* __restrict__ ypre,
                                              const float* __restrict__ Wout,
                                              float* __restrict__ m) {
    int sub = threadIdx.x & 15;
    int idx = blockIdx.x * 16 + (threadIdx.x >> 4);   // 0..1023
    int b = idx >> 8, o = idx & 255;
    const float* yr = ypre + b * DI + sub*32;
    const float* wr = Wout + (size_t)o * DI + sub*32;
    float acc = 0.f;
#pragma unroll
    for (int k = 0; k < 32; k += 4)
        acc = dot4(*(const float4*)(yr+k), *(const float4*)(wr+k), acc);
    acc += __shfl_xor(acc, 1); acc += __shfl_xor(acc, 2);
    acc += __shfl_xor(acc, 4); acc += __shfl_xor(acc, 8);
    if (sub == 0) m[idx] = acc;
}

// ---------------- K8: LSTM cell — one wave per (b,j) ----------------
// quad q = gate (i,f,g,o); 16 lanes per gate split K = 256+512.
__global__ __launch_bounds__(256) void k_lstm(const float* __restrict__ m,
                                              const float* __restrict__ h0,
                                              const float* __restrict__ c0,
                                              const float* __restrict__ Wih,
                                              const float* __restrict__ Whh,
                                              const float* __restrict__ bih,
                                              const float* __restrict__ bhh,
                                              float* __restrict__ out) {
    int lane = threadIdx.x & 63;
    int wid  = threadIdx.x >> 6;
    int p = blockIdx.x * 4 + wid;     // 0..2047
    int b = p >> 9, j = p & (HIDN-1);
    int q = lane >> 4, sub = lane & 15;
    int jj = q * HIDN + j;
    float acc = 0.f;
    {
        const float* wi = Wih + (size_t)jj * DM + sub*16;
        const float* mr = m + b * DM + sub*16;
#pragma unroll
        for (int k = 0; k < 16; k += 4)
            acc = dot4(*(const float4*)(mr+k), *(const float4*)(wi+k), acc);
    }
    {
        const float* wh = Whh + (size_t)jj * HIDN + sub*32;
        const float* hr = h0 + b * HIDN + sub*32;
#pragma unroll
        for (int k = 0; k < 32; k += 4)
            acc = dot4(*(const float4*)(hr+k), *(const float4*)(wh+k), acc);
    }
    if (sub == 0) acc += bih[jj] + bhh[jj];
    acc += __shfl_xor(acc, 1); acc += __shfl_xor(acc, 2);
    acc += __shfl_xor(acc, 4); acc += __shfl_xor(acc, 8);
    float gi = __shfl(acc, 0);
    float gf = __shfl(acc, 16);
    float gg = __shfl(acc, 32);
    float go = __shfl(acc, 48);
    if (lane == 0) {
        int idx = b * HIDN + j;
        float cn = sig_(gf) * c0[idx] + sig_(gi) * tanhf(gg);
        float hn = sig_(go) * tanhf(cn);
        out[idx] = hn;                 // h_new
        out[BB*HIDN + idx] = cn;       // c_new
    }
}

extern "C" void kernel_launch(void* const* d_in, const int* in_sizes, int n_in,
                              void* d_out, int out_size, void* d_ws, size_t ws_size,
                              hipStream_t stream) {
    const float* x     = (const float*)d_in[0];
    const float* h0    = (const float*)d_in[1];
    const float* c0    = (const float*)d_in[2];
    const float* Win   = (const float*)d_in[3];
    const float* convw = (const float*)d_in[4];
    const float* convb = (const float*)d_in[5];
    const float* Wx    = (const float*)d_in[6];
    const float* Wdt   = (const float*)d_in[7];
    const float* bdt   = (const float*)d_in[8];
    const float* Alog  = (const float*)d_in[9];
    const float* Dp    = (const float*)d_in[10];
    const float* Wout  = (const float*)d_in[11];
    const float* Wih   = (const float*)d_in[12];
    const float* Whh   = (const float*)d_in[13];
    const float* bih   = (const float*)d_in[14];
    const float* bhh   = (const float*)d_in[15];

    float* ws   = (float*)d_ws;
    float* xi   = ws;                         // ROWS*DI  (reused as dt after K3)
    float* xs   = xi + (size_t)ROWS*DI;       // ROWS*DI
    float* proj = xs + (size_t)ROWS*DI;       // ROWS*48
    float* hc   = proj + (size_t)ROWS*48;     // BB*DI*DSN*NCH = 524288
    float* Dsum = hc + (size_t)BB*DI*DSN*NCH; // BB*DI*NCH = 32768
    float* zl   = Dsum + (size_t)BB*DI*NCH;   // BB*DI
    float* ypre = zl + (size_t)BB*DI;         // BB*DI
    float* mm   = ypre + (size_t)BB*DI;       // BB*DM
    float* out  = (float*)d_out;

    k_gemm_xi<<<dim3(ROWS/64, DI/64), 256, 0, stream>>>(x, Win, xi);
    k_zlast <<<BB*DI/16, 256, 0, stream>>>(x, Win, zl);
    k_conv  <<<(size_t)ROWS*DI/256, 256, 0, stream>>>(xi, convw, convb, xs);
    k_proj  <<<ROWS/4, 192, 0, stream>>>(xs, Wx, proj);
    k_dt    <<<(size_t)ROWS*DI/256, 256, 0, stream>>>(proj, Wdt, bdt, xi);
    k_scan1 <<<BB*DI*DSN*NCH/256, 256, 0, stream>>>(xi, xs, proj, Alog, hc, Dsum);
    k_scan2 <<<BB*DI*DSN/256, 256, 0, stream>>>(hc, Dsum, Alog, proj, xs, Dp, zl, ypre);
    k_mout  <<<BB*DM/16, 256, 0, stream>>>(ypre, Wout, mm);
    k_lstm  <<<BB*HIDN/4, 256, 0, stream>>>(mm, h0, c0, Wih, Whh, bih, bhh, out);  // 512 blocks: 2048 outputs / 4 waves-per-block
}

// Round 4
// 234.646 us; speedup vs baseline: 2.0058x; 1.3337x over previous
//
#include <hip/hip_runtime.h>
#include <math.h>

#define BB   4
#define LL   2048
#define DM   256
#define DI   512
#define DSN  16
#define HIDN 512
#define NCH  16
#define CHK  128          // LL / NCH
#define ROWS (BB*LL)      // 8192

__device__ __forceinline__ float sig_(float x) { return 1.f / (1.f + __expf(-x)); }
__device__ __forceinline__ float dot4(float4 a, float4 w, float acc) {
    return fmaf(a.x,w.x, fmaf(a.y,w.y, fmaf(a.z,w.z, fmaf(a.w,w.w, acc))));
}

// ---------------- K1: xi = x @ W_in[0:512]^T  (8192x512, K=256) ----------------
__global__ __launch_bounds__(256) void k_gemm_xi(const float* __restrict__ x,
                                                 const float* __restrict__ Win,
                                                 float* __restrict__ xi) {
    __shared__ float As[16][68];   // [k][m], pitch 68 floats = 272 B (16B-aligned)
    __shared__ float Bs[16][68];   // [k][n]
    const int tid = threadIdx.x;
    const int tx = tid & 15, ty = tid >> 4;
    const int m0 = blockIdx.x * 64;
    const int n0 = blockIdx.y * 64;
    const int lr = tid >> 2;          // 0..63
    const int lk = (tid & 3) << 2;    // 0,4,8,12
    float acc[4][4] = {};
    for (int k0 = 0; k0 < DM; k0 += 16) {
        float4 av = *(const float4*)(x   + (size_t)(m0 + lr) * DM + k0 + lk);
        float4 bv = *(const float4*)(Win + (size_t)(n0 + lr) * DM + k0 + lk);
        As[lk+0][lr] = av.x; As[lk+1][lr] = av.y; As[lk+2][lr] = av.z; As[lk+3][lr] = av.w;
        Bs[lk+0][lr] = bv.x; Bs[lk+1][lr] = bv.y; Bs[lk+2][lr] = bv.z; Bs[lk+3][lr] = bv.w;
        __syncthreads();
#pragma unroll
        for (int kk = 0; kk < 16; ++kk) {
            float4 a4 = *(const float4*)&As[kk][ty*4];
            float4 b4 = *(const float4*)&Bs[kk][tx*4];
            float a[4] = {a4.x, a4.y, a4.z, a4.w};
            float b[4] = {b4.x, b4.y, b4.z, b4.w};
#pragma unroll
            for (int i = 0; i < 4; ++i)
#pragma unroll
                for (int j = 0; j < 4; ++j) acc[i][j] = fmaf(a[i], b[j], acc[i][j]);
        }
        __syncthreads();
    }
#pragma unroll
    for (int i = 0; i < 4; ++i) {
        const int m = m0 + ty*4 + i;
#pragma unroll
        for (int j = 0; j < 4; ++j)
            xi[(size_t)m * DI + n0 + tx*4 + j] = acc[i][j];
    }
}

// ---------------- K1b: z_last[b,d] = x[b,L-1,:] . W_in[512+d,:] ----------------
__global__ __launch_bounds__(256) void k_zlast(const float* __restrict__ x,
                                               const float* __restrict__ Win,
                                               float* __restrict__ zl) {
    int sub = threadIdx.x & 15;
    int idx = blockIdx.x * 16 + (threadIdx.x >> 4);   // 0..2047
    int b = idx >> 9, d = idx & (DI-1);
    const float* xr = x + (size_t)(b*LL + LL-1) * DM + sub*16;
    const float* wr = Win + (size_t)(DI + d) * DM + sub*16;
    float acc = 0.f;
#pragma unroll
    for (int k = 0; k < 16; k += 4)
        acc = dot4(*(const float4*)(xr+k), *(const float4*)(wr+k), acc);
    acc += __shfl_xor(acc, 1); acc += __shfl_xor(acc, 2);
    acc += __shfl_xor(acc, 4); acc += __shfl_xor(acc, 8);
    if (sub == 0) zl[idx] = acc;
}

// ---------------- K2: causal depthwise conv (k=4) + SiLU -> xs ----------------
__global__ void k_conv(const float* __restrict__ xi, const float* __restrict__ cw,
                       const float* __restrict__ cb, float* __restrict__ xs) {
    int idx = blockIdx.x * 256 + threadIdx.x;   // over ROWS*DI
    int d = idx & (DI-1);
    int r = idx >> 9;          // b*LL + l
    int l = r & (LL-1);
    float4 w = *(const float4*)(cw + d*4);
    float acc = cb[d];
    if (l >= 3) {
        acc = fmaf(w.x, xi[(size_t)(r-3)*DI + d], acc);
        acc = fmaf(w.y, xi[(size_t)(r-2)*DI + d], acc);
        acc = fmaf(w.z, xi[(size_t)(r-1)*DI + d], acc);
        acc = fmaf(w.w, xi[(size_t)(r  )*DI + d], acc);
    } else {
        const float wk[4] = {w.x, w.y, w.z, w.w};
#pragma unroll
        for (int k = 0; k < 4; ++k) {
            int lt = l - 3 + k;
            if (lt >= 0) acc = fmaf(wk[k], xi[(size_t)(r-3+k)*DI + d], acc);
        }
    }
    xs[idx] = acc * sig_(acc);   // silu
}

// ---------------- K3: proj = xs @ W_xproj^T  (8192 x 48, K=512) ----------------
// LDS-tiled: 16 rows/block, Wx K-chunks staged in LDS, 3 outputs/thread.
#define PR 16
#define KC 64
__global__ __launch_bounds__(256) void k_proj(const float* __restrict__ xs,
                                              const float* __restrict__ Wx,
                                              float* __restrict__ proj) {
    __shared__ float Xs[PR][KC+4];   // pitch 68 floats: 16B-aligned, <=2-way bank alias
    __shared__ float Ws[48][KC+4];
    const int tid = threadIdx.x;
    const int row0 = blockIdx.x * PR;
    const int r  = tid >> 4;          // 0..15
    const int e0 = (tid & 15) * 3;    // 0,3,...,45
    float acc[3] = {0.f, 0.f, 0.f};
    for (int k0 = 0; k0 < DI; k0 += KC) {
#pragma unroll
        for (int i = tid; i < 48*16; i += 256) {     // stage Wx[0:48][k0:k0+64]
            int e = i >> 4, kc = (i & 15) * 4;
            *(float4*)&Ws[e][kc] = *(const float4*)(Wx + (size_t)e*DI + k0 + kc);
        }
        {                                            // stage xs[row0:+16][k0:k0+64]
            int rr = tid >> 4, kc = (tid & 15) * 4;
            *(float4*)&Xs[rr][kc] = *(const float4*)(xs + (size_t)(row0+rr)*DI + k0 + kc);
        }
        __syncthreads();
#pragma unroll
        for (int kk = 0; kk < KC; kk += 4) {
            float4 xv = *(const float4*)&Xs[r][kk];
#pragma unroll
            for (int j = 0; j < 3; ++j)
                acc[j] = dot4(xv, *(const float4*)&Ws[e0+j][kk], acc[j]);
        }
        __syncthreads();
    }
#pragma unroll
    for (int j = 0; j < 3; ++j)
        proj[(size_t)(row0 + r)*48 + e0 + j] = acc[j];
}

// ---------------- K4: dt = softplus(proj[:, :16] @ W_dt^T + b_dt) ----------------
__global__ void k_dt(const float* __restrict__ proj, const float* __restrict__ Wdt,
                     const float* __restrict__ bdt, float* __restrict__ dt) {
    int idx = blockIdx.x * 256 + threadIdx.x;   // over ROWS*DI
    int d = idx & (DI-1);
    int row = idx >> 9;
    const float* pr = proj + (size_t)row * 48;
    const float* wr = Wdt + d * 16;
    float acc = bdt[d];
#pragma unroll
    for (int k = 0; k < 16; k += 4)
        acc = dot4(*(const float4*)(pr+k), *(const float4*)(wr+k), acc);
    dt[idx] = (acc > 20.f) ? acc : log1pf(__expf(acc));   // softplus
}

// ---------------- K5: per-chunk scan ----------------
// lane map (d in LOW bits for coalescing): d=g&511, s=(g>>9)&15, c=(g>>13)&15, b=g>>17
// hc layout [b][s][c][d]; Dsum layout [b][c][d] -> coalesced wave writes.
__global__ __launch_bounds__(256) void k_scan1(const float* __restrict__ dt,
                                               const float* __restrict__ xs,
                                               const float* __restrict__ proj,
                                               const float* __restrict__ Alog,
                                               float* __restrict__ hc,
                                               float* __restrict__ Dsum) {
    int g = blockIdx.x * 256 + threadIdx.x;
    int d = g & (DI-1);
    int s = (g >> 9) & 15;
    int c = (g >> 13) & (NCH-1);
    int b = g >> 17;
    float Af = -__expf(Alog[d*DSN + s]);
    float h = 0.f, Dl = 0.f;
    int rbase = b*LL + c*CHK;
    for (int i = 0; i < CHK; ++i) {
        int r = rbase + i;
        float dtv = dt[(size_t)r*DI + d];                 // coalesced 256B/wave
        float xsv = xs[(size_t)r*DI + d];                 // coalesced
        float bcv = proj[(size_t)r*48 + 16 + s];          // wave-uniform (scalar)
        h = __expf(dtv * Af) * h + dtv * bcv * xsv;
        Dl += dtv;
    }
    hc[(size_t)(((b*16 + s)*16 + c) << 9) + d] = h;       // coalesced
    if (s == 0) Dsum[(size_t)((b*16 + c) << 9) + d] = Dl; // coalesced
}

// ---------------- K6: cross-chunk combine + y_last epilogue ----------------
__global__ __launch_bounds__(256) void k_scan2(const float* __restrict__ hc,
                                               const float* __restrict__ Dsum,
                                               const float* __restrict__ Alog,
                                               const float* __restrict__ proj,
                                               const float* __restrict__ xs,
                                               const float* __restrict__ Dp,
                                               const float* __restrict__ zl,
                                               float* __restrict__ ypre) {
    int g = blockIdx.x * 256 + threadIdx.x;   // 0..32767
    int s = g & 15;
    int d = (g >> 4) & (DI-1);
    int b = g >> 13;
    float Af = -__expf(Alog[d*DSN + s]);
    const float* hcb = hc + (size_t)(((b*16 + s)*16) << 9) + d;   // stride 512 per c
    const float* Db  = Dsum + (size_t)((b*16) << 9) + d;          // stride 512 per c
    float h = 0.f, Ss = 0.f;
#pragma unroll
    for (int c = NCH-1; c >= 0; --c) {
        h = fmaf(__expf(Af * Ss), hcb[(size_t)c << 9], h);
        Ss += Db[(size_t)c << 9];
    }
    int rlast = b*LL + LL - 1;
    float v = h * proj[(size_t)rlast*48 + 32 + s];
    v += __shfl_xor(v, 8);
    v += __shfl_xor(v, 4);
    v += __shfl_xor(v, 2);
    v += __shfl_xor(v, 1);
    if (s == 0) {
        float y = v + xs[(size_t)rlast*DI + d] * Dp[d];
        float z = zl[b*DI + d];
        y *= z * sig_(z);             // * silu(z)
        ypre[b*DI + d] = y;
    }
}

// ---------------- K7: m = y_pre @ W_out^T  (4 x 256, K=512) ----------------
__global__ __launch_bounds__(256) void k_mout(const float* __restrict__ ypre,
                                              const float* __restrict__ Wout,
                                              float* __restrict__ m) {
    int sub = threadIdx.x & 15;
    int idx = blockIdx.x * 16 + (threadIdx.x >> 4);   // 0..1023
    int b = idx >> 8, o = idx & 255;
    const float* yr = ypre + b * DI + sub*32;
    const float* wr = Wout + (size_t)o * DI + sub*32;
    float acc = 0.f;
#pragma unroll
    for (int k = 0; k < 32; k += 4)
        acc = dot4(*(const float4*)(yr+k), *(const float4*)(wr+k), acc);
    acc += __shfl_xor(acc, 1); acc += __shfl_xor(acc, 2);
    acc += __shfl_xor(acc, 4); acc += __shfl_xor(acc, 8);
    if (sub == 0) m[idx] = acc;
}

// ---------------- K8: LSTM cell — one wave per (b,j) ----------------
__global__ __launch_bounds__(256) void k_lstm(const float* __restrict__ m,
                                              const float* __restrict__ h0,
                                              const float* __restrict__ c0,
                                              const float* __restrict__ Wih,
                                              const float* __restrict__ Whh,
                                              const float* __restrict__ bih,
                                              const float* __restrict__ bhh,
                                              float* __restrict__ out) {
    int lane = threadIdx.x & 63;
    int wid  = threadIdx.x >> 6;
    int p = blockIdx.x * 4 + wid;     // 0..2047
    int b = p >> 9, j = p & (HIDN-1);
    int q = lane >> 4, sub = lane & 15;
    int jj = q * HIDN + j;
    float acc = 0.f;
    {
        const float* wi = Wih + (size_t)jj * DM + sub*16;
        const float* mr = m + b * DM + sub*16;
#pragma unroll
        for (int k = 0; k < 16; k += 4)
            acc = dot4(*(const float4*)(mr+k), *(const float4*)(wi+k), acc);
    }
    {
        const float* wh = Whh + (size_t)jj * HIDN + sub*32;
        const float* hr = h0 + b * HIDN + sub*32;
#pragma unroll
        for (int k = 0; k < 32; k += 4)
            acc = dot4(*(const float4*)(hr+k), *(const float4*)(wh+k), acc);
    }
    if (sub == 0) acc += bih[jj] + bhh[jj];
    acc += __shfl_xor(acc, 1); acc += __shfl_xor(acc, 2);
    acc += __shfl_xor(acc, 4); acc += __shfl_xor(acc, 8);
    float gi = __shfl(acc, 0);
    float gf = __shfl(acc, 16);
    float gg = __shfl(acc, 32);
    float go = __shfl(acc, 48);
    if (lane == 0) {
        int idx = b * HIDN + j;
        float cn = sig_(gf) * c0[idx] + sig_(gi) * tanhf(gg);
        float hn = sig_(go) * tanhf(cn);
        out[idx] = hn;                 // h_new
        out[BB*HIDN + idx] = cn;       // c_new
    }
}

extern "C" void kernel_launch(void* const* d_in, const int* in_sizes, int n_in,
                              void* d_out, int out_size, void* d_ws, size_t ws_size,
                              hipStream_t stream) {
    const float* x     = (const float*)d_in[0];
    const float* h0    = (const float*)d_in[1];
    const float* c0    = (const float*)d_in[2];
    const float* Win   = (const float*)d_in[3];
    const float* convw = (const float*)d_in[4];
    const float* convb = (const float*)d_in[5];
    const float* Wx    = (const float*)d_in[6];
    const float* Wdt   = (const float*)d_in[7];
    const float* bdt   = (const float*)d_in[8];
    const float* Alog  = (const float*)d_in[9];
    const float* Dp    = (const float*)d_in[10];
    const float* Wout  = (const float*)d_in[11];
    const float* Wih   = (const float*)d_in[12];
    const float* Whh   = (const float*)d_in[13];
    const float* bih   = (const float*)d_in[14];
    const float* bhh   = (const float*)d_in[15];

    float* ws   = (float*)d_ws;
    float* xi   = ws;                         // ROWS*DI  (reused as dt after K3)
    float* xs   = xi + (size_t)ROWS*DI;       // ROWS*DI
    float* proj = xs + (size_t)ROWS*DI;       // ROWS*48
    float* hc   = proj + (size_t)ROWS*48;     // BB*DSN*NCH*DI = 524288  [b][s][c][d]
    float* Dsum = hc + (size_t)BB*DSN*NCH*DI; // BB*NCH*DI = 32768      [b][c][d]
    float* zl   = Dsum + (size_t)BB*NCH*DI;   // BB*DI
    float* ypre = zl + (size_t)BB*DI;         // BB*DI
    float* mm   = ypre + (size_t)BB*DI;       // BB*DM
    float* out  = (float*)d_out;

    k_gemm_xi<<<dim3(ROWS/64, DI/64), 256, 0, stream>>>(x, Win, xi);
    k_zlast <<<BB*DI/16, 256, 0, stream>>>(x, Win, zl);
    k_conv  <<<(size_t)ROWS*DI/256, 256, 0, stream>>>(xi, convw, convb, xs);
    k_proj  <<<ROWS/PR, 256, 0, stream>>>(xs, Wx, proj);
    k_dt    <<<(size_t)ROWS*DI/256, 256, 0, stream>>>(proj, Wdt, bdt, xi);
    k_scan1 <<<BB*DI*DSN*NCH/256, 256, 0, stream>>>(xi, xs, proj, Alog, hc, Dsum);
    k_scan2 <<<BB*DI*DSN/256, 256, 0, stream>>>(hc, Dsum, Alog, proj, xs, Dp, zl, ypre);
    k_mout  <<<BB*DM/16, 256, 0, stream>>>(ypre, Wout, mm);
    k_lstm  <<<BB*HIDN/4, 256, 0, stream>>>(mm, h0, c0, Wih, Whh, bih, bhh, out);
}

// Round 5
// 201.506 us; speedup vs baseline: 2.3357x; 1.1645x over previous
//
#include <hip/hip_runtime.h>
#include <math.h>

#define BB   4
#define LL   2048
#define DM   256
#define DI   512
#define DSN  16
#define HIDN 512
#define NCH  16
#define CHK  128          // LL / NCH
#define ROWS (BB*LL)      // 8192

typedef __attribute__((ext_vector_type(8))) short s8v;   // 8 bf16 (4 VGPRs)
typedef __attribute__((ext_vector_type(4))) float f4v;   // 4 fp32 acc

__device__ __forceinline__ float sig_(float x) { return 1.f / (1.f + __expf(-x)); }
__device__ __forceinline__ float dot4(float4 a, float4 w, float acc) {
    return fmaf(a.x,w.x, fmaf(a.y,w.y, fmaf(a.z,w.z, fmaf(a.w,w.w, acc))));
}
__device__ __forceinline__ unsigned short rne_bf16(float f) {
    union { float f; unsigned u; } v; v.f = f;
    unsigned r = v.u + 0x7FFFu + ((v.u >> 16) & 1u);
    return (unsigned short)(r >> 16);
}

// ---------------- K0: fp32 -> bf16 convert (x and W_in[0:512]) ----------------
#define XQ (ROWS*DM/4)    // 524288 float4 quads of x
#define WQ (DI*DM/4)      // 32768 quads of Win[0:512]
__global__ __launch_bounds__(256) void k_cvt(const float* __restrict__ x,
                                             const float* __restrict__ Win,
                                             unsigned short* __restrict__ xb,
                                             unsigned short* __restrict__ wb) {
    int i = blockIdx.x * 256 + threadIdx.x;
    if (i < XQ) {
        float4 v = ((const float4*)x)[i];
        ushort4 o = { rne_bf16(v.x), rne_bf16(v.y), rne_bf16(v.z), rne_bf16(v.w) };
        ((ushort4*)xb)[i] = o;
    } else if (i < XQ + WQ) {
        int j = i - XQ;
        float4 v = ((const float4*)Win)[j];
        ushort4 o = { rne_bf16(v.x), rne_bf16(v.y), rne_bf16(v.z), rne_bf16(v.w) };
        ((ushort4*)wb)[j] = o;
    }
}

// ---------------- K1: xi = x @ W_in[0:512]^T via bf16 MFMA ----------------
// 64x64 tile, K staged in two 128-halves. A layout: m=lane&15, k=quad*8+j.
// C/D layout: col=lane&15, row=quad*4+reg  [verified m89/m91].
__global__ __launch_bounds__(256) void k_gemm_mfma(const unsigned short* __restrict__ xb,
                                                   const unsigned short* __restrict__ wb,
                                                   float* __restrict__ xi) {
    __shared__ unsigned short As[64][136];   // pitch 272 B: 16B-aligned, bank-stride 4
    __shared__ unsigned short Bs[64][136];
    const int tid = threadIdx.x;
    const int m0 = blockIdx.x * 64, n0 = blockIdx.y * 64;
    const int lane = tid & 63, wid = tid >> 6;
    const int mrow = (wid << 4) + (lane & 15);
    const int quad = lane >> 4;
    f4v acc[4] = {{0,0,0,0},{0,0,0,0},{0,0,0,0},{0,0,0,0}};
    for (int kh = 0; kh < DM; kh += 128) {
        __syncthreads();
#pragma unroll
        for (int i = tid; i < 64*16; i += 256) {   // 16B chunks: 64 rows x 128 k
            int r = i >> 4, c8 = (i & 15) << 3;
            *(uint4*)&As[r][c8] = *(const uint4*)(xb + (size_t)(m0+r)*DM + kh + c8);
            *(uint4*)&Bs[r][c8] = *(const uint4*)(wb + (size_t)(n0+r)*DM + kh + c8);
        }
        __syncthreads();
#pragma unroll
        for (int ks = 0; ks < 128; ks += 32) {
            s8v a = *(const s8v*)&As[mrow][ks + quad*8];
#pragma unroll
            for (int nt = 0; nt < 4; ++nt) {
                s8v b = *(const s8v*)&Bs[(nt<<4) + (lane & 15)][ks + quad*8];
                acc[nt] = __builtin_amdgcn_mfma_f32_16x16x32_bf16(a, b, acc[nt], 0, 0, 0);
            }
        }
    }
    const int col = lane & 15;
    const int rbase = m0 + (wid << 4) + (quad << 2);
#pragma unroll
    for (int nt = 0; nt < 4; ++nt)
#pragma unroll
        for (int r = 0; r < 4; ++r)
            xi[(size_t)(rbase + r) * DI + n0 + (nt<<4) + col] = acc[nt][r];
}

// ---------------- K1b: z_last[b,d] = x[b,L-1,:] . W_in[512+d,:] ----------------
__global__ __launch_bounds__(256) void k_zlast(const float* __restrict__ x,
                                               const float* __restrict__ Win,
                                               float* __restrict__ zl) {
    int sub = threadIdx.x & 15;
    int idx = blockIdx.x * 16 + (threadIdx.x >> 4);   // 0..2047
    int b = idx >> 9, d = idx & (DI-1);
    const float* xr = x + (size_t)(b*LL + LL-1) * DM + sub*16;
    const float* wr = Win + (size_t)(DI + d) * DM + sub*16;
    float acc = 0.f;
#pragma unroll
    for (int k = 0; k < 16; k += 4)
        acc = dot4(*(const float4*)(xr+k), *(const float4*)(wr+k), acc);
    acc += __shfl_xor(acc, 1); acc += __shfl_xor(acc, 2);
    acc += __shfl_xor(acc, 4); acc += __shfl_xor(acc, 8);
    if (sub == 0) zl[idx] = acc;
}

// ---------------- K2: causal depthwise conv (k=4) + SiLU -> xs ----------------
__global__ void k_conv(const float* __restrict__ xi, const float* __restrict__ cw,
                       const float* __restrict__ cb, float* __restrict__ xs) {
    int idx = blockIdx.x * 256 + threadIdx.x;   // over ROWS*DI
    int d = idx & (DI-1);
    int r = idx >> 9;          // b*LL + l
    int l = r & (LL-1);
    float4 w = *(const float4*)(cw + d*4);
    float acc = cb[d];
    if (l >= 3) {
        acc = fmaf(w.x, xi[(size_t)(r-3)*DI + d], acc);
        acc = fmaf(w.y, xi[(size_t)(r-2)*DI + d], acc);
        acc = fmaf(w.z, xi[(size_t)(r-1)*DI + d], acc);
        acc = fmaf(w.w, xi[(size_t)(r  )*DI + d], acc);
    } else {
        const float wk[4] = {w.x, w.y, w.z, w.w};
#pragma unroll
        for (int k = 0; k < 4; ++k) {
            int lt = l - 3 + k;
            if (lt >= 0) acc = fmaf(wk[k], xi[(size_t)(r-3+k)*DI + d], acc);
        }
    }
    xs[idx] = acc * sig_(acc);   // silu
}

// ---------------- K3: proj = xs @ W_xproj^T fused with dt = softplus(.) ----------------
#define PR 16
#define KC 64
__global__ __launch_bounds__(256) void k_projdt(const float* __restrict__ xs,
                                                const float* __restrict__ Wx,
                                                const float* __restrict__ Wdt,
                                                const float* __restrict__ bdt,
                                                float* __restrict__ proj,
                                                float* __restrict__ dt) {
    __shared__ float Xs[PR][KC+4];   // pitch 68 floats
    __shared__ float Ws[48][KC+4];
    __shared__ float Ps[PR][48];
    const int tid = threadIdx.x;
    const int row0 = blockIdx.x * PR;
    const int r  = tid >> 4;          // 0..15
    const int e0 = (tid & 15) * 3;    // 0,3,...,45
    float acc[3] = {0.f, 0.f, 0.f};
    for (int k0 = 0; k0 < DI; k0 += KC) {
#pragma unroll
        for (int i = tid; i < 48*16; i += 256) {     // stage Wx[0:48][k0:k0+64]
            int e = i >> 4, kc = (i & 15) * 4;
            *(float4*)&Ws[e][kc] = *(const float4*)(Wx + (size_t)e*DI + k0 + kc);
        }
        {                                            // stage xs[row0:+16][k0:k0+64]
            int rr = tid >> 4, kc = (tid & 15) * 4;
            *(float4*)&Xs[rr][kc] = *(const float4*)(xs + (size_t)(row0+rr)*DI + k0 + kc);
        }
        __syncthreads();
#pragma unroll
        for (int kk = 0; kk < KC; kk += 4) {
            float4 xv = *(const float4*)&Xs[r][kk];
#pragma unroll
            for (int j = 0; j < 3; ++j)
                acc[j] = dot4(xv, *(const float4*)&Ws[e0+j][kk], acc[j]);
        }
        __syncthreads();
    }
#pragma unroll
    for (int j = 0; j < 3; ++j) {
        proj[(size_t)(row0 + r)*48 + e0 + j] = acc[j];
        Ps[r][e0 + j] = acc[j];
    }
    __syncthreads();
    // dt phase: thread handles d = tid and d + 256 for all 16 rows
    const int d0 = tid;
    float w0[16], w1[16];
#pragma unroll
    for (int e = 0; e < 16; e += 4) {
        float4 a = *(const float4*)(Wdt + d0*16 + e);
        w0[e]=a.x; w0[e+1]=a.y; w0[e+2]=a.z; w0[e+3]=a.w;
        float4 bq = *(const float4*)(Wdt + (d0+256)*16 + e);
        w1[e]=bq.x; w1[e+1]=bq.y; w1[e+2]=bq.z; w1[e+3]=bq.w;
    }
    float b0 = bdt[d0], b1 = bdt[d0+256];
#pragma unroll
    for (int row = 0; row < PR; ++row) {
        float a0 = b0, a1 = b1;
#pragma unroll
        for (int e = 0; e < 16; ++e) {
            float p = Ps[row][e];                 // broadcast read
            a0 = fmaf(p, w0[e], a0);
            a1 = fmaf(p, w1[e], a1);
        }
        size_t base = (size_t)(row0 + row) * DI;
        dt[base + d0]       = (a0 > 20.f) ? a0 : log1pf(__expf(a0));
        dt[base + d0 + 256] = (a1 > 20.f) ? a1 : log1pf(__expf(a1));
    }
}

// ---------------- K5: per-chunk scan ----------------
// lane map (d in LOW bits): d=g&511, s=(g>>9)&15, c=(g>>13)&15, b=g>>17
// hc layout [b][s][c][d]; Dsum layout [b][c][d]
__global__ __launch_bounds__(256) void k_scan1(const float* __restrict__ dt,
                                               const float* __restrict__ xs,
                                               const float* __restrict__ proj,
                                               const float* __restrict__ Alog,
                                               float* __restrict__ hc,
                                               float* __restrict__ Dsum) {
    int g = blockIdx.x * 256 + threadIdx.x;
    int d = g & (DI-1);
    int s = (g >> 9) & 15;
    int c = (g >> 13) & (NCH-1);
    int b = g >> 17;
    float Af = -__expf(Alog[d*DSN + s]);
    float h = 0.f, Dl = 0.f;
    int rbase = b*LL + c*CHK;
    for (int i = 0; i < CHK; ++i) {
        int r = rbase + i;
        float dtv = dt[(size_t)r*DI + d];                 // coalesced
        float xsv = xs[(size_t)r*DI + d];                 // coalesced
        float bcv = proj[(size_t)r*48 + 16 + s];          // wave-uniform
        h = __expf(dtv * Af) * h + dtv * bcv * xsv;
        Dl += dtv;
    }
    hc[(size_t)(((b*16 + s)*16 + c) << 9) + d] = h;
    if (s == 0) Dsum[(size_t)((b*16 + c) << 9) + d] = Dl;
}

// ---------------- K6: cross-chunk combine + y_last epilogue ----------------
__global__ __launch_bounds__(256) void k_scan2(const float* __restrict__ hc,
                                               const float* __restrict__ Dsum,
                                               const float* __restrict__ Alog,
                                               const float* __restrict__ proj,
                                               const float* __restrict__ xs,
                                               const float* __restrict__ Dp,
                                               const float* __restrict__ zl,
                                               float* __restrict__ ypre) {
    int g = blockIdx.x * 256 + threadIdx.x;   // 0..32767
    int s = g & 15;
    int d = (g >> 4) & (DI-1);
    int b = g >> 13;
    float Af = -__expf(Alog[d*DSN + s]);
    const float* hcb = hc + (size_t)(((b*16 + s)*16) << 9) + d;   // stride 512 per c
    const float* Db  = Dsum + (size_t)((b*16) << 9) + d;          // stride 512 per c
    float h = 0.f, Ss = 0.f;
#pragma unroll
    for (int c = NCH-1; c >= 0; --c) {
        h = fmaf(__expf(Af * Ss), hcb[(size_t)c << 9], h);
        Ss += Db[(size_t)c << 9];
    }
    int rlast = b*LL + LL - 1;
    float v = h * proj[(size_t)rlast*48 + 32 + s];
    v += __shfl_xor(v, 8);
    v += __shfl_xor(v, 4);
    v += __shfl_xor(v, 2);
    v += __shfl_xor(v, 1);
    if (s == 0) {
        float y = v + xs[(size_t)rlast*DI + d] * Dp[d];
        float z = zl[b*DI + d];
        y *= z * sig_(z);             // * silu(z)
        ypre[b*DI + d] = y;
    }
}

// ---------------- K7: m = y_pre @ W_out^T  (4 x 256, K=512) ----------------
__global__ __launch_bounds__(256) void k_mout(const float* __restrict__ ypre,
                                              const float* __restrict__ Wout,
                                              float* __restrict__ m) {
    int sub = threadIdx.x & 15;
    int idx = blockIdx.x * 16 + (threadIdx.x >> 4);   // 0..1023
    int b = idx >> 8, o = idx & 255;
    const float* yr = ypre + b * DI + sub*32;
    const float* wr = Wout + (size_t)o * DI + sub*32;
    float acc = 0.f;
#pragma unroll
    for (int k = 0; k < 32; k += 4)
        acc = dot4(*(const float4*)(yr+k), *(const float4*)(wr+k), acc);
    acc += __shfl_xor(acc, 1); acc += __shfl_xor(acc, 2);
    acc += __shfl_xor(acc, 4); acc += __shfl_xor(acc, 8);
    if (sub == 0) m[idx] = acc;
}

// ---------------- K8: LSTM cell — one wave per (b,j) ----------------
__global__ __launch_bounds__(256) void k_lstm(const float* __restrict__ m,
                                              const float* __restrict__ h0,
                                              const float* __restrict__ c0,
                                              const float* __restrict__ Wih,
                                              const float* __restrict__ Whh,
                                              const float* __restrict__ bih,
                                              const float* __restrict__ bhh,
                                              float* __restrict__ out) {
    int lane = threadIdx.x & 63;
    int wid  = threadIdx.x >> 6;
    int p = blockIdx.x * 4 + wid;     // 0..2047
    int b = p >> 9, j = p & (HIDN-1);
    int q = lane >> 4, sub = lane & 15;
    int jj = q * HIDN + j;
    float acc = 0.f;
    {
        const float* wi = Wih + (size_t)jj * DM + sub*16;
        const float* mr = m + b * DM + sub*16;
#pragma unroll
        for (int k = 0; k < 16; k += 4)
            acc = dot4(*(const float4*)(mr+k), *(const float4*)(wi+k), acc);
    }
    {
        const float* wh = Whh + (size_t)jj * HIDN + sub*32;
        const float* hr = h0 + b * HIDN + sub*32;
#pragma unroll
        for (int k = 0; k < 32; k += 4)
            acc = dot4(*(const float4*)(hr+k), *(const float4*)(wh+k), acc);
    }
    if (sub == 0) acc += bih[jj] + bhh[jj];
    acc += __shfl_xor(acc, 1); acc += __shfl_xor(acc, 2);
    acc += __shfl_xor(acc, 4); acc += __shfl_xor(acc, 8);
    float gi = __shfl(acc, 0);
    float gf = __shfl(acc, 16);
    float gg = __shfl(acc, 32);
    float go = __shfl(acc, 48);
    if (lane == 0) {
        int idx = b * HIDN + j;
        float cn = sig_(gf) * c0[idx] + sig_(gi) * tanhf(gg);
        float hn = sig_(go) * tanhf(cn);
        out[idx] = hn;                 // h_new
        out[BB*HIDN + idx] = cn;       // c_new
    }
}

extern "C" void kernel_launch(void* const* d_in, const int* in_sizes, int n_in,
                              void* d_out, int out_size, void* d_ws, size_t ws_size,
                              hipStream_t stream) {
    const float* x     = (const float*)d_in[0];
    const float* h0    = (const float*)d_in[1];
    const float* c0    = (const float*)d_in[2];
    const float* Win   = (const float*)d_in[3];
    const float* convw = (const float*)d_in[4];
    const float* convb = (const float*)d_in[5];
    const float* Wx    = (const float*)d_in[6];
    const float* Wdt   = (const float*)d_in[7];
    const float* bdt   = (const float*)d_in[8];
    const float* Alog  = (const float*)d_in[9];
    const float* Dp    = (const float*)d_in[10];
    const float* Wout  = (const float*)d_in[11];
    const float* Wih   = (const float*)d_in[12];
    const float* Whh   = (const float*)d_in[13];
    const float* bih   = (const float*)d_in[14];
    const float* bhh   = (const float*)d_in[15];

    float* ws   = (float*)d_ws;
    float* xi   = ws;                         // ROWS*DI  (reused as dt buffer)
    float* xs   = xi + (size_t)ROWS*DI;       // ROWS*DI
    float* proj = xs + (size_t)ROWS*DI;       // ROWS*48
    float* hc   = proj + (size_t)ROWS*48;     // BB*DSN*NCH*DI  [b][s][c][d]
    float* Dsum = hc + (size_t)BB*DSN*NCH*DI; // BB*NCH*DI      [b][c][d]
    float* zl   = Dsum + (size_t)BB*NCH*DI;   // BB*DI
    float* ypre = zl + (size_t)BB*DI;         // BB*DI
    float* mm   = ypre + (size_t)BB*DI;       // BB*DM
    unsigned short* xb = (unsigned short*)(mm + (size_t)BB*DM);   // ROWS*DM bf16
    unsigned short* wb = xb + (size_t)ROWS*DM;                    // DI*DM bf16
    float* out  = (float*)d_out;

    k_cvt      <<<(XQ+WQ)/256, 256, 0, stream>>>(x, Win, xb, wb);
    k_gemm_mfma<<<dim3(ROWS/64, DI/64), 256, 0, stream>>>(xb, wb, xi);
    k_zlast    <<<BB*DI/16, 256, 0, stream>>>(x, Win, zl);
    k_conv     <<<(size_t)ROWS*DI/256, 256, 0, stream>>>(xi, convw, convb, xs);
    k_projdt   <<<ROWS/PR, 256, 0, stream>>>(xs, Wx, Wdt, bdt, proj, xi /*dt*/);
    k_scan1    <<<BB*DI*DSN*NCH/256, 256, 0, stream>>>(xi, xs, proj, Alog, hc, Dsum);
    k_scan2    <<<BB*DI*DSN/256, 256, 0, stream>>>(hc, Dsum, Alog, proj, xs, Dp, zl, ypre);
    k_mout     <<<BB*DM/16, 256, 0, stream>>>(ypre, Wout, mm);
    k_lstm     <<<BB*HIDN/4, 256, 0, stream>>>(mm, h0, c0, Wih, Whh, bih, bhh, out);
}